// Round 1
// baseline (1240.151 us; speedup 1.0000x reference)
//
#include <hip/hip_runtime.h>

#define T_STEPS 256
#define B_ROWS  1024
#define NX_ 256
#define NY_ 64
#define NU_ 64
#define ND_ 32

typedef _Float16 half8 __attribute__((ext_vector_type(8)));
typedef float    f32x4 __attribute__((ext_vector_type(4)));

#define MFMA16(a,b,c) __builtin_amdgcn_mfma_f32_16x16x32_f16((a),(b),(c),0,0,0)

#define XPITCH 264              // padded LDS row pitch (halfs): 33 dwords -> conflict-free b128
#define XBUFSZ (16*XPITCH)

__device__ __forceinline__ half8 cvt8(f32x4 a, f32x4 b) {
  half8 h;
  h[0]=(_Float16)a[0]; h[1]=(_Float16)a[1]; h[2]=(_Float16)a[2]; h[3]=(_Float16)a[3];
  h[4]=(_Float16)b[0]; h[5]=(_Float16)b[1]; h[6]=(_Float16)b[2]; h[7]=(_Float16)b[3];
  return h;
}

extern "C" __global__ __launch_bounds__(512)
void ssm_fused(const float* __restrict__ x0,
               const float* __restrict__ U,
               const float* __restrict__ Dd,
               const float* __restrict__ Wx,
               const float* __restrict__ bx,
               const float* __restrict__ Wu,
               const float* __restrict__ bu,
               const float* __restrict__ Wd,
               const float* __restrict__ bd,
               const float* __restrict__ Wy,
               const float* __restrict__ by,
               float* __restrict__ Xout,
               float* __restrict__ Yout,
               float* __restrict__ Rout)
{
  __shared__ __align__(16) _Float16 xb[2*XBUFSZ];     // double-buffered x (f16)
  __shared__ __align__(16) _Float16 wyl[64*XPITCH];   // Wy staged f16
  __shared__ float red[64];

  const int tid  = threadIdx.x;
  const int lane = tid & 63;
  const int w    = tid >> 6;     // wave 0..7
  const int q    = lane >> 4;    // quad 0..3
  const int n16  = lane & 15;
  const int b0   = blockIdx.x * 16;   // 16 batch rows per block
  const int c0   = w * 32;            // this wave's xn column slice

  // ---- stage Wy into LDS (f16) ----
  for (int i = tid; i < 64*32; i += 512) {
    int row = i >> 5, ch = i & 31;
    const float* s = Wy + row*NX_ + ch*8;
    _Float16* dst = &wyl[row*XPITCH + ch*8];
    #pragma unroll
    for (int j=0;j<8;j++) dst[j] = (_Float16)s[j];
  }
  // ---- stage x0 into xb[0] (f16); 512 threads * 8 elems = 16*256 ----
  {
    int row = tid >> 5, ch = tid & 31;
    const float* s = x0 + (size_t)(b0+row)*NX_ + ch*8;
    _Float16* dst = &xb[row*XPITCH + ch*8];
    #pragma unroll
    for (int j=0;j<8;j++) dst[j] = (_Float16)s[j];
  }

  // ---- Wx B-fragments, hi+lo f16 split (systematic error ~2^-22) ----
  // B-frag layout (16x16x32): n = lane&15 (Wx row = xn col), k = q*8+j within k-tile
  half8 Wh[2][8], Wl[2][8];
  #pragma unroll
  for (int nt=0; nt<2; nt++) {
    const int row = c0 + nt*16 + n16;
    #pragma unroll
    for (int kk=0; kk<8; kk++) {
      const float* s = Wx + row*NX_ + kk*32 + q*8;
      half8 h, l;
      #pragma unroll
      for (int j=0;j<8;j++){
        float v = s[j];
        _Float16 hi = (_Float16)v;
        h[j] = hi;
        l[j] = (_Float16)(v - (float)hi);
      }
      Wh[nt][kk]=h; Wl[nt][kk]=l;
    }
  }
  // ---- Wu / Wd fragments (single f16: not iterated, error not amplified) ----
  half8 WuF[2][2];
  #pragma unroll
  for (int nt=0;nt<2;nt++){
    const int row=c0+nt*16+n16;
    #pragma unroll
    for(int kk=0;kk<2;kk++){
      const float* s=Wu+row*NU_+kk*32+q*8; half8 h;
      #pragma unroll
      for(int j=0;j<8;j++) h[j]=(_Float16)s[j];
      WuF[nt][kk]=h;
    }
  }
  half8 WdF[2];
  #pragma unroll
  for(int nt=0;nt<2;nt++){
    const int row=c0+nt*16+n16;
    const float* s=Wd+row*ND_+q*8; half8 h;
    #pragma unroll
    for(int j=0;j<8;j++) h[j]=(_Float16)s[j];
    WdF[nt]=h;
  }
  // ---- bias slices ----
  const float bxs[2] = { bx[c0+n16], bx[c0+16+n16] };
  const float bus[2] = { bu[c0+n16], bu[c0+16+n16] };
  const float bds[2] = { bd[c0+n16], bd[c0+16+n16] };
  const float bys    = (w<4) ? by[w*16+n16] : 0.f;

  // ---- xc carry (fp32) in C/D acc layout: row = q*4+r, col = c0+nt*16+n16 ----
  float xcv[2][4];
  #pragma unroll
  for(int nt=0;nt<2;nt++)
    #pragma unroll
    for(int r=0;r<4;r++)
      xcv[nt][r] = x0[(size_t)(b0+q*4+r)*NX_ + c0+nt*16+n16];

  float st[7];
  #pragma unroll
  for(int i=0;i<7;i++) st[i]=0.f;

  __syncthreads();

  for (int t=0; t<T_STEPS; t++) {
    const _Float16* xr = xb + (t&1)*XBUFSZ;
    _Float16*       xw = xb + ((t&1)^1)*XBUFSZ;

    // ---- u/d global loads issued first (latency hidden under Wx MFMAs) ----
    // A-frag: m = n16 (batch row), k = kk*32 + q*8 + j
    const float* usrc = U  + ((size_t)t*B_ROWS + b0 + n16)*NU_;
    const float* dsrc = Dd + ((size_t)t*B_ROWS + b0 + n16)*ND_;
    f32x4 u0a = *(const f32x4*)(usrc + q*8);
    f32x4 u0b = *(const f32x4*)(usrc + q*8 + 4);
    f32x4 u1a = *(const f32x4*)(usrc + 32 + q*8);
    f32x4 u1b = *(const f32x4*)(usrc + 32 + q*8 + 4);
    f32x4 d0a = *(const f32x4*)(dsrc + q*8);
    f32x4 d0b = *(const f32x4*)(dsrc + q*8 + 4);

    // ---- xn = x @ WxT (hi + lo), acc seeded with bx ----
    f32x4 xn[2];
    xn[0] = (f32x4){bxs[0],bxs[0],bxs[0],bxs[0]};
    xn[1] = (f32x4){bxs[1],bxs[1],bxs[1],bxs[1]};
    #pragma unroll
    for (int kk=0;kk<8;kk++){
      half8 xa = *(const half8*)(xr + n16*XPITCH + kk*32 + q*8);
      xn[0] = MFMA16(xa, Wh[0][kk], xn[0]);
      xn[1] = MFMA16(xa, Wh[1][kk], xn[1]);
      xn[0] = MFMA16(xa, Wl[0][kk], xn[0]);
      xn[1] = MFMA16(xa, Wl[1][kk], xn[1]);
    }

    // ---- fu = u@WuT + bu ; fd = d@WdT + bd ----
    half8 uf0 = cvt8(u0a,u0b), uf1 = cvt8(u1a,u1b), df = cvt8(d0a,d0b);
    f32x4 fu[2], fd[2];
    fu[0] = (f32x4){bus[0],bus[0],bus[0],bus[0]};
    fu[1] = (f32x4){bus[1],bus[1],bus[1],bus[1]};
    fd[0] = (f32x4){bds[0],bds[0],bds[0],bds[0]};
    fd[1] = (f32x4){bds[1],bds[1],bds[1],bds[1]};
    fu[0] = MFMA16(uf0, WuF[0][0], fu[0]);  fu[0] = MFMA16(uf1, WuF[0][1], fu[0]);
    fu[1] = MFMA16(uf0, WuF[1][0], fu[1]);  fu[1] = MFMA16(uf1, WuF[1][1], fu[1]);
    fd[0] = MFMA16(df,  WdF[0],    fd[0]);
    fd[1] = MFMA16(df,  WdF[1],    fd[1]);

    // ---- combine, stats, X store, LDS write ----
    const size_t xrowbase = (size_t)t*(B_ROWS*NX_) + (size_t)b0*NX_;
    #pragma unroll
    for (int nt=0;nt<2;nt++){
      #pragma unroll
      for (int r=0;r<4;r++){
        float f  = fu[nt][r];
        float g  = fd[nt][r];
        float z  = xn[nt][r] + f + g;       // fp32 carry
        float zc = xcv[nt][r];
        float r0 = fmaxf(-1.f - z, 0.f);    // relu(-xn + XMIN)
        float r1 = fmaxf( z - 1.f, 0.f);    // relu(xn - XMAX)
        float r2 = fmaxf(-1.f - f, 0.f);    // relu(-fu + UMIN)
        float r3 = fmaxf( f - 1.f, 0.f);    // relu(fu - UMAX)
        float g0 = fmaxf(-1.f - g, 0.f);
        float g1 = fmaxf( g - 1.f, 0.f);
        float dz = z - zc;
        st[0]+=r0; st[1]+=r1; st[2]+=r2; st[3]+=r3;
        st[4]+=dz*dz; st[5]+=r2+r3; st[6]+=g0+g1;
        Xout[xrowbase + (size_t)(q*4+r)*NX_ + (c0+nt*16+n16)] = z;
        xw[(q*4+r)*XPITCH + c0+nt*16+n16] = (_Float16)z;
        xcv[nt][r] = z;
      }
    }
    __syncthreads();   // xw complete; also protects buffer rotation (1 barrier/step)

    // ---- y = xn @ WyT + by  (waves 0-3; waves 4-7 run ahead into t+1) ----
    if (w < 4) {
      f32x4 ya = (f32x4){bys,bys,bys,bys};
      #pragma unroll
      for (int kk=0;kk<8;kk++){
        half8 xa = *(const half8*)(xw + n16*XPITCH + kk*32 + q*8);
        half8 wb = *(const half8*)(&wyl[(w*16+n16)*XPITCH + kk*32 + q*8]);
        ya = MFMA16(xa, wb, ya);
      }
      const size_t ybase = (size_t)t*(B_ROWS*NY_) + (size_t)b0*NY_ + w*16 + n16;
      #pragma unroll
      for (int r=0;r<4;r++)
        Yout[ybase + (size_t)(q*4+r)*NY_] = ya[r];
    }
  }

  // ---- reg_error reduction: lane -> wave -> block -> global atomic ----
  #pragma unroll
  for (int off=32; off>=1; off>>=1){
    #pragma unroll
    for (int i=0;i<7;i++) st[i] += __shfl_down(st[i], off, 64);
  }
  __syncthreads();
  if (lane==0){
    #pragma unroll
    for (int i=0;i<7;i++) red[w*8+i] = st[i];
  }
  __syncthreads();
  if (tid==0){
    float s = 0.f;
    for (int ww=0; ww<8; ww++)
      for (int i=0;i<7;i++) s += red[ww*8+i];
    // Q * sum(stats), stats = mean over T*B*NX of each term
    atomicAdd(Rout, s * (0.2f/67108864.0f));
  }
}

extern "C" void kernel_launch(void* const* d_in, const int* in_sizes, int n_in,
                              void* d_out, int out_size, void* d_ws, size_t ws_size,
                              hipStream_t stream)
{
  const float* x0=(const float*)d_in[0];
  const float* U =(const float*)d_in[1];
  const float* Dd=(const float*)d_in[2];
  const float* Wx=(const float*)d_in[3];
  const float* bx=(const float*)d_in[4];
  const float* Wu=(const float*)d_in[5];
  const float* bu=(const float*)d_in[6];
  const float* Wd=(const float*)d_in[7];
  const float* bd=(const float*)d_in[8];
  const float* Wy=(const float*)d_in[9];
  const float* by=(const float*)d_in[10];

  float* X = (float*)d_out;
  float* Y = X + (size_t)T_STEPS*B_ROWS*NX_;
  float* R = Y + (size_t)T_STEPS*B_ROWS*NY_;

  hipMemsetAsync(R, 0, sizeof(float), stream);   // reg_error accumulator <- 0
  ssm_fused<<<dim3(64), dim3(512), 0, stream>>>(x0,U,Dd,Wx,bx,Wu,bu,Wd,bd,Wy,by,X,Y,R);
}

// Round 2
// 822.380 us; speedup vs baseline: 1.5080x; 1.5080x over previous
//
#include <hip/hip_runtime.h>

#define T_STEPS 256
#define B_ROWS  1024
#define NX_ 256
#define NY_ 64
#define NU_ 64
#define ND_ 32

#define CHUNK   32
#define NCHUNK  8          // T_STEPS / CHUNK

typedef _Float16 half8 __attribute__((ext_vector_type(8)));
typedef float    f32x4 __attribute__((ext_vector_type(4)));

#define MFMA16(a,b,c) __builtin_amdgcn_mfma_f32_16x16x32_f16((a),(b),(c),0,0,0)

#define XPITCH 264              // padded LDS row pitch (halfs): 2-way max on b128
#define XBUFSZ (16*XPITCH)

__device__ __forceinline__ half8 cvt8(f32x4 a, f32x4 b) {
  half8 h;
  h[0]=(_Float16)a[0]; h[1]=(_Float16)a[1]; h[2]=(_Float16)a[2]; h[3]=(_Float16)a[3];
  h[4]=(_Float16)b[0]; h[5]=(_Float16)b[1]; h[6]=(_Float16)b[2]; h[7]=(_Float16)b[3];
  return h;
}

// ---------------------------------------------------------------------------
// out = in @ in (256x256 f32). from_wx: in-matrix is M = Wx^T read from Wx.
// M[r][k] = Wx[k][r]. One block per output row, one thread per column.
// ---------------------------------------------------------------------------
extern "C" __global__ __launch_bounds__(256)
void matsq(const float* __restrict__ src, float* __restrict__ dst, int from_wx)
{
  const int r = blockIdx.x, c = threadIdx.x;
  float acc = 0.f;
  if (from_wx) {
    for (int k = 0; k < NX_; k++) acc += src[k*NX_ + r] * src[c*NX_ + k];
  } else {
    for (int k = 0; k < NX_; k++) acc += src[r*NX_ + k] * src[k*NX_ + c];
  }
  dst[r*NX_ + c] = acc;
}

// ---------------------------------------------------------------------------
// Phase 1: per (row-group, chunk) scan from zero state (chunk 0: from x0).
// Stores only the chunk-final state (f32) to Lend[chunk][B][NX].
// ---------------------------------------------------------------------------
extern "C" __global__ __launch_bounds__(512)
void phase1(const float* __restrict__ x0,
            const float* __restrict__ U,
            const float* __restrict__ Dd,
            const float* __restrict__ Wx,
            const float* __restrict__ bx,
            const float* __restrict__ Wu,
            const float* __restrict__ bu,
            const float* __restrict__ Wd,
            const float* __restrict__ bd,
            float* __restrict__ Lend)
{
  __shared__ __align__(16) _Float16 xb[2*XBUFSZ];

  const int tid  = threadIdx.x;
  const int lane = tid & 63;
  const int w    = tid >> 6;
  const int q    = lane >> 4;
  const int n16  = lane & 15;
  const int b0   = blockIdx.x * 16;
  const int ck   = blockIdx.y;          // chunk 0..6
  const int t0   = ck * CHUNK;
  const int c0   = w * 32;

  // ---- stage init state into xb[0] ----
  if (ck == 0) {
    int row = tid >> 5, ch = tid & 31;
    const float* s = x0 + (size_t)(b0+row)*NX_ + ch*8;
    _Float16* dst = &xb[row*XPITCH + ch*8];
    #pragma unroll
    for (int j=0;j<8;j++) dst[j] = (_Float16)s[j];
  } else {
    for (int i = tid; i < XBUFSZ; i += 512) xb[i] = (_Float16)0.f;
  }

  // ---- Wx hi/lo B-frags ----
  half8 Wh[2][8], Wl[2][8];
  #pragma unroll
  for (int nt=0; nt<2; nt++) {
    const int row = c0 + nt*16 + n16;
    #pragma unroll
    for (int kk=0; kk<8; kk++) {
      const float* s = Wx + row*NX_ + kk*32 + q*8;
      half8 h, l;
      #pragma unroll
      for (int j=0;j<8;j++){
        float v = s[j];
        _Float16 hi = (_Float16)v;
        h[j] = hi;
        l[j] = (_Float16)(v - (float)hi);
      }
      Wh[nt][kk]=h; Wl[nt][kk]=l;
    }
  }
  half8 WuF[2][2];
  #pragma unroll
  for (int nt=0;nt<2;nt++){
    const int row=c0+nt*16+n16;
    #pragma unroll
    for(int kk=0;kk<2;kk++){
      const float* s=Wu+row*NU_+kk*32+q*8; half8 h;
      #pragma unroll
      for(int j=0;j<8;j++) h[j]=(_Float16)s[j];
      WuF[nt][kk]=h;
    }
  }
  half8 WdF[2];
  #pragma unroll
  for(int nt=0;nt<2;nt++){
    const int row=c0+nt*16+n16;
    const float* s=Wd+row*ND_+q*8; half8 h;
    #pragma unroll
    for(int j=0;j<8;j++) h[j]=(_Float16)s[j];
    WdF[nt]=h;
  }
  const float bxs[2] = { bx[c0+n16], bx[c0+16+n16] };
  const float bus[2] = { bu[c0+n16], bu[c0+16+n16] };
  const float bds[2] = { bd[c0+n16], bd[c0+16+n16] };

  float xcv[2][4];
  #pragma unroll
  for(int nt=0;nt<2;nt++)
    #pragma unroll
    for(int r=0;r<4;r++)
      xcv[nt][r] = (ck==0) ? x0[(size_t)(b0+q*4+r)*NX_ + c0+nt*16+n16] : 0.f;

  __syncthreads();

  for (int tt=0; tt<CHUNK; tt++) {
    const int t = t0 + tt;
    const _Float16* xr = xb + (tt&1)*XBUFSZ;
    _Float16*       xw = xb + ((tt&1)^1)*XBUFSZ;

    const float* usrc = U  + ((size_t)t*B_ROWS + b0 + n16)*NU_;
    const float* dsrc = Dd + ((size_t)t*B_ROWS + b0 + n16)*ND_;
    f32x4 u0a = *(const f32x4*)(usrc + q*8);
    f32x4 u0b = *(const f32x4*)(usrc + q*8 + 4);
    f32x4 u1a = *(const f32x4*)(usrc + 32 + q*8);
    f32x4 u1b = *(const f32x4*)(usrc + 32 + q*8 + 4);
    f32x4 d0a = *(const f32x4*)(dsrc + q*8);
    f32x4 d0b = *(const f32x4*)(dsrc + q*8 + 4);

    f32x4 xn[2];
    xn[0] = (f32x4){bxs[0],bxs[0],bxs[0],bxs[0]};
    xn[1] = (f32x4){bxs[1],bxs[1],bxs[1],bxs[1]};
    #pragma unroll
    for (int kk=0;kk<8;kk++){
      half8 xa = *(const half8*)(xr + n16*XPITCH + kk*32 + q*8);
      xn[0] = MFMA16(xa, Wh[0][kk], xn[0]);
      xn[1] = MFMA16(xa, Wh[1][kk], xn[1]);
      xn[0] = MFMA16(xa, Wl[0][kk], xn[0]);
      xn[1] = MFMA16(xa, Wl[1][kk], xn[1]);
    }

    half8 uf0 = cvt8(u0a,u0b), uf1 = cvt8(u1a,u1b), df = cvt8(d0a,d0b);
    f32x4 fu[2], fd[2];
    fu[0] = (f32x4){bus[0],bus[0],bus[0],bus[0]};
    fu[1] = (f32x4){bus[1],bus[1],bus[1],bus[1]};
    fd[0] = (f32x4){bds[0],bds[0],bds[0],bds[0]};
    fd[1] = (f32x4){bds[1],bds[1],bds[1],bds[1]};
    fu[0] = MFMA16(uf0, WuF[0][0], fu[0]);  fu[0] = MFMA16(uf1, WuF[0][1], fu[0]);
    fu[1] = MFMA16(uf0, WuF[1][0], fu[1]);  fu[1] = MFMA16(uf1, WuF[1][1], fu[1]);
    fd[0] = MFMA16(df,  WdF[0],    fd[0]);
    fd[1] = MFMA16(df,  WdF[1],    fd[1]);

    #pragma unroll
    for (int nt=0;nt<2;nt++){
      #pragma unroll
      for (int r=0;r<4;r++){
        float z = xn[nt][r] + fu[nt][r] + fd[nt][r];
        xw[(q*4+r)*XPITCH + c0+nt*16+n16] = (_Float16)z;
        xcv[nt][r] = z;
      }
    }
    __syncthreads();
  }

  // store chunk-final state
  float* dst = Lend + (size_t)ck*(B_ROWS*NX_);
  #pragma unroll
  for (int nt=0;nt<2;nt++)
    #pragma unroll
    for (int r=0;r<4;r++)
      dst[(size_t)(b0+q*4+r)*NX_ + c0+nt*16+n16] = xcv[nt][r];
}

// ---------------------------------------------------------------------------
// Combine: S[1] = Lend[0]; S[k] = S[k-1] @ P + Lend[k-1], k = 2..7.
// P = M^32 (f32, row-major [k][n]); hi/lo f16 fragments.
// ---------------------------------------------------------------------------
extern "C" __global__ __launch_bounds__(512)
void combine(const float* __restrict__ P,
             const float* __restrict__ Lend,
             float* __restrict__ S)
{
  __shared__ __align__(16) _Float16 xb[2*XBUFSZ];

  const int tid  = threadIdx.x;
  const int lane = tid & 63;
  const int w    = tid >> 6;
  const int q    = lane >> 4;
  const int n16  = lane & 15;
  const int b0   = blockIdx.x * 16;
  const int c0   = w * 32;
  const size_t BN = (size_t)B_ROWS*NX_;

  // P B-frags hi/lo: element (n = c0+nt*16+n16, k = kk*32+q*8+j) -> P[k*NX_+n]
  half8 Ph[2][8], Pl[2][8];
  #pragma unroll
  for (int nt=0; nt<2; nt++) {
    const int n = c0 + nt*16 + n16;
    #pragma unroll
    for (int kk=0; kk<8; kk++) {
      half8 h, l;
      #pragma unroll
      for (int j=0;j<8;j++){
        float v = P[(size_t)(kk*32 + q*8 + j)*NX_ + n];
        _Float16 hi = (_Float16)v;
        h[j] = hi;
        l[j] = (_Float16)(v - (float)hi);
      }
      Ph[nt][kk]=h; Pl[nt][kk]=l;
    }
  }

  // stage s = Lend[0] into xb[0] (f16) and copy to S[1]
  {
    int row = tid >> 5, ch = tid & 31;
    const float* s = Lend + (size_t)(b0+row)*NX_ + ch*8;
    float*       o = S    + (size_t)(b0+row)*NX_ + ch*8;
    _Float16* dst = &xb[row*XPITCH + ch*8];
    #pragma unroll
    for (int j=0;j<8;j++){ float v = s[j]; dst[j] = (_Float16)v; o[j] = v; }
  }
  __syncthreads();

  for (int k=2; k<=7; k++) {
    const int rp = (k-2)&1;
    const _Float16* xr = xb + rp*XBUFSZ;
    _Float16*       xw = xb + (rp^1)*XBUFSZ;

    // seed acc with Lend[k-1]
    const float* lsrc = Lend + (size_t)(k-1)*BN;
    f32x4 xn[2];
    #pragma unroll
    for (int nt=0;nt<2;nt++)
      #pragma unroll
      for (int r=0;r<4;r++)
        xn[nt][r] = lsrc[(size_t)(b0+q*4+r)*NX_ + c0+nt*16+n16];

    #pragma unroll
    for (int kk=0;kk<8;kk++){
      half8 xa = *(const half8*)(xr + n16*XPITCH + kk*32 + q*8);
      xn[0] = MFMA16(xa, Ph[0][kk], xn[0]);
      xn[1] = MFMA16(xa, Ph[1][kk], xn[1]);
      xn[0] = MFMA16(xa, Pl[0][kk], xn[0]);
      xn[1] = MFMA16(xa, Pl[1][kk], xn[1]);
    }

    float* sdst = S + (size_t)(k-1)*BN;
    #pragma unroll
    for (int nt=0;nt<2;nt++)
      #pragma unroll
      for (int r=0;r<4;r++){
        float z = xn[nt][r];
        sdst[(size_t)(b0+q*4+r)*NX_ + c0+nt*16+n16] = z;
        xw[(q*4+r)*XPITCH + c0+nt*16+n16] = (_Float16)z;
      }
    __syncthreads();
  }
}

// ---------------------------------------------------------------------------
// Phase 2: full work per chunk from correct init state.
// ---------------------------------------------------------------------------
extern "C" __global__ __launch_bounds__(512)
void phase2(const float* __restrict__ x0,
            const float* __restrict__ U,
            const float* __restrict__ Dd,
            const float* __restrict__ Wx,
            const float* __restrict__ bx,
            const float* __restrict__ Wu,
            const float* __restrict__ bu,
            const float* __restrict__ Wd,
            const float* __restrict__ bd,
            const float* __restrict__ Wy,
            const float* __restrict__ by,
            const float* __restrict__ S,
            float* __restrict__ Xout,
            float* __restrict__ Yout,
            float* __restrict__ Rout)
{
  __shared__ __align__(16) _Float16 xb[2*XBUFSZ];
  __shared__ __align__(16) _Float16 wyl[64*XPITCH];
  __shared__ float red[64];

  const int tid  = threadIdx.x;
  const int lane = tid & 63;
  const int w    = tid >> 6;
  const int q    = lane >> 4;
  const int n16  = lane & 15;
  const int b0   = blockIdx.x * 16;
  const int ck   = blockIdx.y;
  const int t0   = ck * CHUNK;
  const int c0   = w * 32;

  const float* init = (ck==0) ? x0 : (S + (size_t)(ck-1)*B_ROWS*NX_);

  for (int i = tid; i < 64*32; i += 512) {
    int row = i >> 5, ch = i & 31;
    const float* s = Wy + row*NX_ + ch*8;
    _Float16* dst = &wyl[row*XPITCH + ch*8];
    #pragma unroll
    for (int j=0;j<8;j++) dst[j] = (_Float16)s[j];
  }
  {
    int row = tid >> 5, ch = tid & 31;
    const float* s = init + (size_t)(b0+row)*NX_ + ch*8;
    _Float16* dst = &xb[row*XPITCH + ch*8];
    #pragma unroll
    for (int j=0;j<8;j++) dst[j] = (_Float16)s[j];
  }

  half8 Wh[2][8], Wl[2][8];
  #pragma unroll
  for (int nt=0; nt<2; nt++) {
    const int row = c0 + nt*16 + n16;
    #pragma unroll
    for (int kk=0; kk<8; kk++) {
      const float* s = Wx + row*NX_ + kk*32 + q*8;
      half8 h, l;
      #pragma unroll
      for (int j=0;j<8;j++){
        float v = s[j];
        _Float16 hi = (_Float16)v;
        h[j] = hi;
        l[j] = (_Float16)(v - (float)hi);
      }
      Wh[nt][kk]=h; Wl[nt][kk]=l;
    }
  }
  half8 WuF[2][2];
  #pragma unroll
  for (int nt=0;nt<2;nt++){
    const int row=c0+nt*16+n16;
    #pragma unroll
    for(int kk=0;kk<2;kk++){
      const float* s=Wu+row*NU_+kk*32+q*8; half8 h;
      #pragma unroll
      for(int j=0;j<8;j++) h[j]=(_Float16)s[j];
      WuF[nt][kk]=h;
    }
  }
  half8 WdF[2];
  #pragma unroll
  for(int nt=0;nt<2;nt++){
    const int row=c0+nt*16+n16;
    const float* s=Wd+row*ND_+q*8; half8 h;
    #pragma unroll
    for(int j=0;j<8;j++) h[j]=(_Float16)s[j];
    WdF[nt]=h;
  }
  const float bxs[2] = { bx[c0+n16], bx[c0+16+n16] };
  const float bus[2] = { bu[c0+n16], bu[c0+16+n16] };
  const float bds[2] = { bd[c0+n16], bd[c0+16+n16] };
  const float bys    = (w<4) ? by[w*16+n16] : 0.f;

  float xcv[2][4];
  #pragma unroll
  for(int nt=0;nt<2;nt++)
    #pragma unroll
    for(int r=0;r<4;r++)
      xcv[nt][r] = init[(size_t)(b0+q*4+r)*NX_ + c0+nt*16+n16];

  float st[7];
  #pragma unroll
  for(int i=0;i<7;i++) st[i]=0.f;

  __syncthreads();

  for (int tt=0; tt<CHUNK; tt++) {
    const int t = t0 + tt;
    const _Float16* xr = xb + (tt&1)*XBUFSZ;
    _Float16*       xw = xb + ((tt&1)^1)*XBUFSZ;

    const float* usrc = U  + ((size_t)t*B_ROWS + b0 + n16)*NU_;
    const float* dsrc = Dd + ((size_t)t*B_ROWS + b0 + n16)*ND_;
    f32x4 u0a = *(const f32x4*)(usrc + q*8);
    f32x4 u0b = *(const f32x4*)(usrc + q*8 + 4);
    f32x4 u1a = *(const f32x4*)(usrc + 32 + q*8);
    f32x4 u1b = *(const f32x4*)(usrc + 32 + q*8 + 4);
    f32x4 d0a = *(const f32x4*)(dsrc + q*8);
    f32x4 d0b = *(const f32x4*)(dsrc + q*8 + 4);

    f32x4 xn[2];
    xn[0] = (f32x4){bxs[0],bxs[0],bxs[0],bxs[0]};
    xn[1] = (f32x4){bxs[1],bxs[1],bxs[1],bxs[1]};
    #pragma unroll
    for (int kk=0;kk<8;kk++){
      half8 xa = *(const half8*)(xr + n16*XPITCH + kk*32 + q*8);
      xn[0] = MFMA16(xa, Wh[0][kk], xn[0]);
      xn[1] = MFMA16(xa, Wh[1][kk], xn[1]);
      xn[0] = MFMA16(xa, Wl[0][kk], xn[0]);
      xn[1] = MFMA16(xa, Wl[1][kk], xn[1]);
    }

    half8 uf0 = cvt8(u0a,u0b), uf1 = cvt8(u1a,u1b), df = cvt8(d0a,d0b);
    f32x4 fu[2], fd[2];
    fu[0] = (f32x4){bus[0],bus[0],bus[0],bus[0]};
    fu[1] = (f32x4){bus[1],bus[1],bus[1],bus[1]};
    fd[0] = (f32x4){bds[0],bds[0],bds[0],bds[0]};
    fd[1] = (f32x4){bds[1],bds[1],bds[1],bds[1]};
    fu[0] = MFMA16(uf0, WuF[0][0], fu[0]);  fu[0] = MFMA16(uf1, WuF[0][1], fu[0]);
    fu[1] = MFMA16(uf0, WuF[1][0], fu[1]);  fu[1] = MFMA16(uf1, WuF[1][1], fu[1]);
    fd[0] = MFMA16(df,  WdF[0],    fd[0]);
    fd[1] = MFMA16(df,  WdF[1],    fd[1]);

    const size_t xrowbase = (size_t)t*(B_ROWS*NX_) + (size_t)b0*NX_;
    #pragma unroll
    for (int nt=0;nt<2;nt++){
      #pragma unroll
      for (int r=0;r<4;r++){
        float f  = fu[nt][r];
        float g  = fd[nt][r];
        float z  = xn[nt][r] + f + g;
        float zc = xcv[nt][r];
        float r0 = fmaxf(-1.f - z, 0.f);
        float r1 = fmaxf( z - 1.f, 0.f);
        float r2 = fmaxf(-1.f - f, 0.f);
        float r3 = fmaxf( f - 1.f, 0.f);
        float g0 = fmaxf(-1.f - g, 0.f);
        float g1 = fmaxf( g - 1.f, 0.f);
        float dz = z - zc;
        st[0]+=r0; st[1]+=r1; st[2]+=r2; st[3]+=r3;
        st[4]+=dz*dz; st[5]+=r2+r3; st[6]+=g0+g1;
        Xout[xrowbase + (size_t)(q*4+r)*NX_ + (c0+nt*16+n16)] = z;
        xw[(q*4+r)*XPITCH + c0+nt*16+n16] = (_Float16)z;
        xcv[nt][r] = z;
      }
    }
    __syncthreads();

    if (w < 4) {
      f32x4 ya = (f32x4){bys,bys,bys,bys};
      #pragma unroll
      for (int kk=0;kk<8;kk++){
        half8 xa = *(const half8*)(xw + n16*XPITCH + kk*32 + q*8);
        half8 wb = *(const half8*)(&wyl[(w*16+n16)*XPITCH + kk*32 + q*8]);
        ya = MFMA16(xa, wb, ya);
      }
      const size_t ybase = (size_t)t*(B_ROWS*NY_) + (size_t)b0*NY_ + w*16 + n16;
      #pragma unroll
      for (int r=0;r<4;r++)
        Yout[ybase + (size_t)(q*4+r)*NY_] = ya[r];
    }
  }

  #pragma unroll
  for (int off=32; off>=1; off>>=1){
    #pragma unroll
    for (int i=0;i<7;i++) st[i] += __shfl_down(st[i], off, 64);
  }
  __syncthreads();
  if (lane==0){
    #pragma unroll
    for (int i=0;i<7;i++) red[w*8+i] = st[i];
  }
  __syncthreads();
  if (tid==0){
    float s = 0.f;
    for (int ww=0; ww<8; ww++)
      for (int i=0;i<7;i++) s += red[ww*8+i];
    atomicAdd(Rout, s * (0.2f/67108864.0f));
  }
}

extern "C" void kernel_launch(void* const* d_in, const int* in_sizes, int n_in,
                              void* d_out, int out_size, void* d_ws, size_t ws_size,
                              hipStream_t stream)
{
  const float* x0=(const float*)d_in[0];
  const float* U =(const float*)d_in[1];
  const float* Dd=(const float*)d_in[2];
  const float* Wx=(const float*)d_in[3];
  const float* bx=(const float*)d_in[4];
  const float* Wu=(const float*)d_in[5];
  const float* bu=(const float*)d_in[6];
  const float* Wd=(const float*)d_in[7];
  const float* bd=(const float*)d_in[8];
  const float* Wy=(const float*)d_in[9];
  const float* by=(const float*)d_in[10];

  float* X = (float*)d_out;
  float* Y = X + (size_t)T_STEPS*B_ROWS*NX_;
  float* R = Y + (size_t)T_STEPS*B_ROWS*NY_;

  // workspace layout (floats)
  float* B0   = (float*)d_ws;                 // 65536
  float* B1   = B0 + 65536;                   // 65536
  float* Lend = B1 + 65536;                   // 7 * 1024*256
  float* S    = Lend + (size_t)7*B_ROWS*NX_;  // 7 * 1024*256

  hipMemsetAsync(R, 0, sizeof(float), stream);

  // P = (Wx^T)^32 via repeated squaring (f32)
  matsq<<<dim3(256), dim3(256), 0, stream>>>(Wx, B1, 1);  // M^2
  matsq<<<dim3(256), dim3(256), 0, stream>>>(B1, B0, 0);  // M^4
  matsq<<<dim3(256), dim3(256), 0, stream>>>(B0, B1, 0);  // M^8
  matsq<<<dim3(256), dim3(256), 0, stream>>>(B1, B0, 0);  // M^16
  matsq<<<dim3(256), dim3(256), 0, stream>>>(B0, B1, 0);  // M^32 -> P = B1

  phase1<<<dim3(64,7), dim3(512), 0, stream>>>(x0,U,Dd,Wx,bx,Wu,bu,Wd,bd,Lend);
  combine<<<dim3(64), dim3(512), 0, stream>>>(B1, Lend, S);
  phase2<<<dim3(64,8), dim3(512), 0, stream>>>(x0,U,Dd,Wx,bx,Wu,bu,Wd,bd,Wy,by,S,X,Y,R);
}